// Round 28
// baseline (228.292 us; speedup 1.0000x reference)
//
#include <hip/hip_runtime.h>
#include <math.h>

#define NHEADS 12
#define HD 64
#define BB 16
#define NN 1025
#define CC 768
#define MM (BB * NN)                       // 16400
#define QSZ ((size_t)BB * NHEADS * NN * HD)   // 12,595,200
#define NNP 1032                           // padded t-stride for V^T
#define VTSZ ((size_t)BB * NHEADS * HD * NNP)

typedef __attribute__((ext_vector_type(8))) short short8;
typedef __attribute__((ext_vector_type(4))) float f32x4;
typedef __attribute__((ext_vector_type(4))) unsigned short us4;
typedef __attribute__((ext_vector_type(4))) unsigned int u32x4;
typedef unsigned short us;

typedef __attribute__((address_space(3))) unsigned int lds_u32;
typedef const __attribute__((address_space(1))) unsigned int g_u32;

__device__ __forceinline__ void gload16(const void* g, void* l) {
    __builtin_amdgcn_global_load_lds((g_u32*)g, (lds_u32*)l, 16, 0, 0);
}

__device__ __forceinline__ int imin(int a, int b) { return a < b ? a : b; }

__device__ __forceinline__ us f2h(float f) {          // fp32 -> fp16 bits (RTE)
    _Float16 h = (_Float16)f;
    return __builtin_bit_cast(unsigned short, h);
}
__device__ __forceinline__ float h2f(us b) {
    return (float)__builtin_bit_cast(_Float16, b);
}
__device__ __forceinline__ unsigned pkrtz(float a, float b) {  // 2xfp16 packed
    return __builtin_bit_cast(unsigned, __builtin_amdgcn_cvt_pkrtz(a, b));
}

// ---------------- split_x: fp32 -> plain fp16 [M][768] -----------------------------
__global__ __launch_bounds__(256) void split_x(const float* __restrict__ src,
                                               us* __restrict__ xc) {
    size_t e = ((size_t)blockIdx.x * 256 + threadIdx.x) * 8;
    float4 a = *(const float4*)(src + e);
    float4 b = *(const float4*)(src + e + 4);
    float v[8] = {a.x, a.y, a.z, a.w, b.x, b.y, b.z, b.w};
    short8 h;
#pragma unroll
    for (int j = 0; j < 8; ++j) h[j] = (short)f2h(v[j]);
    *(short8*)(xc + e) = h;
}

// ---------------- tsplit: W [K][N] fp32 -> W^T plain fp16 [N][K] -------------------
__global__ __launch_bounds__(256) void tsplit(const float* __restrict__ w,
                                              us* __restrict__ wc, int N) {
    __shared__ float tile[64][65];
    const int t = threadIdx.x;
    const int n0 = blockIdx.x * 64, k0 = blockIdx.y * 64;
    {
        int kr = t & 63, so = t >> 6;
#pragma unroll
        for (int g = 0; g < 4; ++g) {
            int c = (so * 4 + g) * 4;
            float4 v = *(const float4*)(w + (size_t)(k0 + kr) * N + n0 + c);
            tile[kr][c + 0] = v.x; tile[kr][c + 1] = v.y;
            tile[kr][c + 2] = v.z; tile[kr][c + 3] = v.w;
        }
    }
    __syncthreads();
    int nr = t & 63, half = t >> 6;     // 16 consecutive k per thread
    short8 h0, h1;
#pragma unroll
    for (int j = 0; j < 8; ++j) h0[j] = (short)f2h(tile[half * 16 + j][nr]);
#pragma unroll
    for (int j = 0; j < 8; ++j) h1[j] = (short)f2h(tile[half * 16 + 8 + j][nr]);
    size_t o = (size_t)(n0 + nr) * CC + k0 + half * 16;
    *(short8*)(wc + o)     = h0;
    *(short8*)(wc + o + 8) = h1;
}

// ---------------- gemm_mfma: 256Mx128N tile, 512 thr (8 waves), gload_lds ----------
// MODE 0: qkv epilogue with FUSED RMSNorm+RoPE for Q/K (LUT in reused LDS).
template<int MODE>
__global__ __launch_bounds__(512) void gemm_mfma(
    const us* __restrict__ A,      // W^T plain fp16 [N][768]
    const us* __restrict__ B,      // X/O plain fp16 [M][768]
    us* __restrict__ Q, us* __restrict__ K, us* __restrict__ Vth,
    const float* __restrict__ qnw, const float* __restrict__ knw,
    float* __restrict__ fout, const float* __restrict__ bias) {
    __shared__ __align__(16) char lds[49152];
    char* ldsA = lds;              // 16 KB: 128 rows x 128B
    char* ldsB = lds + 16384;      // 32 KB: 256 rows x 128B
    const int tid = threadIdx.x;
    const int lane = tid & 63, wv = tid >> 6;   // 8 waves
    const int wn = wv >> 2, wm = wv & 3;        // 2n x 4m
    const int g = lane >> 4;

    // bijective XCD swizzle (m204)
    const int gx = gridDim.x;
    const int nwg = gx * gridDim.y;
    const int lin = blockIdx.y * gx + blockIdx.x;
    const int qq = nwg >> 3, rr = nwg & 7;
    const int xcd = lin & 7, idx = lin >> 3;
    const int wgid = (xcd < rr ? xcd * (qq + 1) : rr * (qq + 1) + (xcd - rr) * qq) + idx;
    const int n0 = (wgid % gx) * 128, m0 = (wgid / gx) * 256;

    f32x4 acc[4][4];
    const f32x4 fz = {0.f, 0.f, 0.f, 0.f};
#pragma unroll
    for (int a = 0; a < 4; ++a)
#pragma unroll
        for (int b = 0; b < 4; ++b) acc[a][b] = fz;

    const int srow = (wv << 3) + (lane >> 3);   // 0..63
    const int cb   = (lane & 7) ^ ((lane >> 3) & 7);
    size_t aoff[2], boff[4];
#pragma unroll
    for (int i = 0; i < 2; ++i)
        aoff[i] = (size_t)(n0 + i * 64 + srow) * CC + cb * 8;
#pragma unroll
    for (int i = 0; i < 4; ++i)
        boff[i] = (size_t)imin(m0 + i * 64 + srow, MM - 1) * CC + cb * 8;
    const int wdst = wv * 1024;    // (wv*8 rows) * 128B

    for (int t = 0; t < CC / 64; ++t) {
#pragma unroll
        for (int i = 0; i < 2; ++i)
            gload16(A + aoff[i] + t * 64, ldsA + i * 8192 + wdst);
#pragma unroll
        for (int i = 0; i < 4; ++i)
            gload16(B + boff[i] + t * 64, ldsB + i * 8192 + wdst);
        __syncthreads();

        const int j  = lane >> 4;
        const int rl = lane & 15;
#pragma unroll
        for (int kh = 0; kh < 2; ++kh) {
            short8 af[4];
#pragma unroll
            for (int nc = 0; nc < 4; ++nc) {
                int ra = wn * 64 + nc * 16 + rl;
                af[nc] = *(const short8*)(ldsA + ra * 128 + ((((kh << 2) + j) ^ (ra & 7)) << 4));
            }
            __builtin_amdgcn_s_setprio(1);
#pragma unroll
            for (int mc = 0; mc < 4; ++mc) {
                int rb = wm * 64 + mc * 16 + rl;
                short8 bf = *(const short8*)(ldsB + rb * 128 + ((((kh << 2) + j) ^ (rb & 7)) << 4));
#pragma unroll
                for (int nc = 0; nc < 4; ++nc)
                    acc[nc][mc] = __builtin_amdgcn_mfma_f32_16x16x32_f16(af[nc], bf, acc[nc][mc], 0, 0, 0);
            }
            __builtin_amdgcn_s_setprio(0);
        }
        __syncthreads();
    }

    if (MODE == 0) {
        const int s = n0 / CC;
        if (s < 2) {
            // ---- fused RMSNorm + RoPE on Q/K rows (row m fully held by 4 g-lanes) --
            float2* lut = (float2*)lds;       // reuse LDS: 512 x (cos,sin)
            {
                int pos = tid >> 4, jj = tid & 15;
                float ang = (float)pos * exp2f((float)jj * (-13.287712379549449f / 16.0f));
                lut[tid] = make_float2(cosf(ang), sinf(ang));
            }
            __syncthreads();
            const float* wvec = (s == 0) ? qnw : knw;
            float wr[4][4];
#pragma unroll
            for (int nc = 0; nc < 4; ++nc)
#pragma unroll
                for (int r = 0; r < 4; ++r) wr[nc][r] = wvec[nc * 16 + g * 4 + r];
            const float qscale = (s == 0) ? 0.125f * 1.4426950408889634f : 1.0f;
            const int head = (n0 - s * CC + wn * 64) >> 6;   // wave-uniform
            us* dst = (s == 0) ? Q : K;

#pragma unroll
            for (int mc = 0; mc < 4; ++mc) {
                int m = m0 + wm * 64 + mc * 16 + (lane & 15);
                if (m >= MM) continue;
                int b = m / NN, t = m - b * NN;
                float v[4][4];
#pragma unroll
                for (int nc = 0; nc < 4; ++nc)
#pragma unroll
                    for (int r = 0; r < 4; ++r) v[nc][r] = acc[nc][mc][r];
                float ss = 0.f;
#pragma unroll
                for (int nc = 0; nc < 4; ++nc)
#pragma unroll
                    for (int r = 0; r < 4; ++r) ss += v[nc][r] * v[nc][r];
                ss += __shfl_xor(ss, 16);
                ss += __shfl_xor(ss, 32);
                float rn = 1.0f / sqrtf(ss * (1.0f / 64.0f) + 1e-6f);
#pragma unroll
                for (int nc = 0; nc < 4; ++nc)
#pragma unroll
                    for (int r = 0; r < 4; ++r) v[nc][r] *= rn * wr[nc][r];
                if (t > 0) {
                    int px = (t - 1) & 31, py = (t - 1) >> 5;
#pragma unroll
                    for (int r = 0; r < 4; ++r) {
                        float2 ex = lut[px * 16 + g * 4 + r];
                        float2 ey = lut[py * 16 + g * 4 + r];
                        float n0v = v[0][r] * ex.x - v[2][r] * ex.y;
                        float n1v = v[1][r] * ex.x - v[3][r] * ex.y;
                        float n2v = v[2][r] * ey.x + v[0][r] * ey.y;
                        float n3v = v[3][r] * ey.x + v[1][r] * ey.y;
                        v[0][r] = n0v; v[1][r] = n1v; v[2][r] = n2v; v[3][r] = n3v;
                    }
                }
                int bh = b * NHEADS + head;
                size_t rbase = ((size_t)bh * NN + t) * HD;
#pragma unroll
                for (int nc = 0; nc < 4; ++nc) {
                    us4 h4;
#pragma unroll
                    for (int r = 0; r < 4; ++r) h4[r] = f2h(v[nc][r] * qscale);
                    *(us4*)(dst + rbase + nc * 16 + g * 4) = h4;
                }
            }
        } else {
            // ---- V epilogue (transposed store, pads zeroed) ----
#pragma unroll
            for (int mc = 0; mc < 4; ++mc) {
                int m = m0 + wm * 64 + mc * 16 + (lane & 15);
                if (m >= MM) continue;
                int b = m / NN, t = m - b * NN;
#pragma unroll
                for (int nc = 0; nc < 4; ++nc) {
                    int nin = (n0 - 2 * CC) + wn * 64 + nc * 16 + g * 4;  // head*64+d
                    int head = nin >> 6;
                    int dd = nin & 63;
                    int bh = b * NHEADS + head;
#pragma unroll
                    for (int r = 0; r < 4; ++r) {
                        size_t idx2 = ((size_t)bh * HD + dd + r) * NNP + t;
                        Vth[idx2] = f2h(acc[nc][mc][r]);
                        if (t == NN - 1) {
#pragma unroll
                            for (int tt = 1; tt <= 7; ++tt) Vth[idx2 + tt] = 0;
                        }
                    }
                }
            }
        }
    } else {
#pragma unroll
        for (int mc = 0; mc < 4; ++mc) {
            int m = m0 + wm * 64 + mc * 16 + (lane & 15);
            if (m >= MM) continue;
#pragma unroll
            for (int nc = 0; nc < 4; ++nc) {
                int n = n0 + wn * 64 + nc * 16 + (g << 2);
                float4 o = {acc[nc][mc][0] + bias[n + 0], acc[nc][mc][1] + bias[n + 1],
                            acc[nc][mc][2] + bias[n + 2], acc[nc][mc][3] + bias[n + 3]};
                *(float4*)(fout + (size_t)m * CC + n) = o;
            }
        }
    }
}

// ---------------- attn: gload_lds dbuf (pre-permuted src), hoisted K reads ---------
// sigma(pp) = p5<<5 | p3<<4 | p2<<3 | p4<<2 | p1<<1 | p0  (inverse of write perm)
__global__ __launch_bounds__(256) void attn_mfma(
    const us* __restrict__ Q, const us* __restrict__ K,
    const us* __restrict__ Vth, us* __restrict__ OC) {
    __shared__ __align__(16) char smem[36864];
    const int tid = threadIdx.x;
    const int lane = tid & 63, wv = tid >> 6;
    const int g = lane >> 4, qi = lane & 15;

    int lin = blockIdx.x;                  // 0..1727
    int xcd = lin & 7, loc = lin >> 3;     // loc 0..215
    int bh  = (loc / 9) * 8 + xcd;         // 0..191
    int qb  = loc - (loc / 9) * 9;         // 0..8
    const int q0 = qb * 128;

    const size_t kbase0 = (size_t)bh * NN * HD;
    const size_t vbase0 = (size_t)bh * HD * NNP;

    short8 qf[2][2];
#pragma unroll
    for (int h = 0; h < 2; ++h) {
        int qr = imin(q0 + (wv << 5) + (h << 4) + qi, NN - 1);
        const us* qp = Q + kbase0 + (size_t)qr * HD + (g << 3);
        qf[h][0] = *(const short8*)(qp);
        qf[h][1] = *(const short8*)(qp + 32);
    }

    f32x4 oa[2][5];                // [h][4] = denominator (V ones-rows)
    const f32x4 fz = {0.f, 0.f, 0.f, 0.f};
#pragma unroll
    for (int h = 0; h < 2; ++h)
#pragma unroll
        for (int db = 0; db < 5; ++db) oa[h][db] = fz;

    const int VB = 8192;           // V offset within a buffer (buffer = 18432 B)
    const int BUFS = 18432;

    // ones rows d=64..79 of BOTH V buffers
    *(uint2*)(smem + VB + 8192 + tid * 8) = (uint2){0x3C003C00u, 0x3C003C00u};
    *(uint2*)(smem + BUFS + VB + 8192 + tid * 8) = (uint2){0x3C003C00u, 0x3C003C00u};

    int rbase[2];
#pragma unroll
    for (int ks = 0; ks < 2; ++ks)
        rbase[ks] = qi * 128 + (((ks << 6) + (g << 4)) ^ ((qi & 7) << 4));

    // gload_lds staging: lane l of wave's 8-row chunk -> LDS row pp, slot l&7.
    // K source pre-permuted: true key sigma(pp), chunk (l&7)^(pp&7).
    const int lrow = lane >> 3, lslot = lane & 7;
    const us* ks_[2];
    const us* vs_[2];
#pragma unroll
    for (int i = 0; i < 2; ++i) {
        int pp  = (wv << 4) + (i << 3) + lrow;
        int sig = ((pp >> 5) << 5) | (((pp >> 3) & 1) << 4) |
                  (((pp >> 2) & 1) << 3) | (((pp >> 4) & 1) << 2) | (pp & 3);
        ks_[i] = K + kbase0 + (size_t)sig * HD + ((lslot ^ (pp & 7)) << 3);
        vs_[i] = Vth + vbase0 + (size_t)pp * NNP + ((lslot ^ lrow) << 3);
    }
    const int kd0 = wv * 2048, kd1 = wv * 2048 + 1024;

    // prologue: stage tile 0 into buf0
    gload16(ks_[0], smem + kd0);
    gload16(ks_[1], smem + kd1);
    gload16(vs_[0], smem + VB + kd0);
    gload16(vs_[1], smem + VB + kd1);
    ks_[0] += 64 * HD; ks_[1] += 64 * HD; vs_[0] += 64; vs_[1] += 64;
    __syncthreads();

    auto step = [&](int t, char* buf, char* bufn, bool stage) {
        if (stage) {               // issue t+1 loads into the other buffer
            gload16(ks_[0], bufn + kd0);
            gload16(ks_[1], bufn + kd1);
            gload16(vs_[0], bufn + VB + kd0);
            gload16(vs_[1], bufn + VB + kd1);
            ks_[0] += 64 * HD; ks_[1] += 64 * HD; vs_[0] += 64; vs_[1] += 64;
        }
        const int j0 = t * 64;

        // S^T = K·Q, both q-halves share each K fragment (single read)
        f32x4 sc[2][4];
#pragma unroll
        for (int h = 0; h < 2; ++h)
#pragma unroll
            for (int c = 0; c < 4; ++c) sc[h][c] = fz;
        __builtin_amdgcn_s_setprio(1);
#pragma unroll
        for (int ks = 0; ks < 2; ++ks)
#pragma unroll
            for (int c = 0; c < 4; ++c) {
                short8 kfh = *(const short8*)(buf + rbase[ks] + c * 2048);
                sc[0][c] = __builtin_amdgcn_mfma_f32_16x16x32_f16(kfh, qf[0][ks], sc[0][c], 0, 0, 0);
                sc[1][c] = __builtin_amdgcn_mfma_f32_16x16x32_f16(kfh, qf[1][ks], sc[1][c], 0, 0, 0);
            }
        __builtin_amdgcn_s_setprio(0);

        if (j0 + 64 > NN) {        // TRUE key of frag (c,r) = 32(c>>1)+8g+4(c&1)+r
#pragma unroll
            for (int c = 0; c < 4; ++c)
#pragma unroll
                for (int r = 0; r < 4; ++r)
                    if (j0 + ((c >> 1) << 5) + (g << 3) + ((c & 1) << 2) + r >= NN) {
                        sc[0][c][r] = -1e30f;
                        sc[1][c][r] = -1e30f;
                    }
        }

        short8 pa[2][2];
#pragma unroll
        for (int h = 0; h < 2; ++h)
#pragma unroll
            for (int ks = 0; ks < 2; ++ks) {
                u32x4 w;
                w[0] = pkrtz(exp2f(sc[h][2 * ks][0]), exp2f(sc[h][2 * ks][1]));
                w[1] = pkrtz(exp2f(sc[h][2 * ks][2]), exp2f(sc[h][2 * ks][3]));
                w[2] = pkrtz(exp2f(sc[h][2 * ks + 1][0]), exp2f(sc[h][2 * ks + 1][1]));
                w[3] = pkrtz(exp2f(sc[h][2 * ks + 1][2]), exp2f(sc[h][2 * ks + 1][3]));
                pa[h][ks] = __builtin_bit_cast(short8, w);
            }

        // O += P·V; l += P·ones (db=4); V fragment shared across halves
        __builtin_amdgcn_s_setprio(1);
#pragma unroll
        for (int ks = 0; ks < 2; ++ks)
#pragma unroll
            for (int db = 0; db < 5; ++db) {
                short8 vfh = *(const short8*)(buf + VB + rbase[ks] + db * 2048);
                oa[0][db] = __builtin_amdgcn_mfma_f32_16x16x32_f16(pa[0][ks], vfh, oa[0][db], 0, 0, 0);
                oa[1][db] = __builtin_amdgcn_mfma_f32_16x16x32_f16(pa[1][ks], vfh, oa[1][db], 0, 0, 0);
            }
        __builtin_amdgcn_s_setprio(0);
        __syncthreads();
    };

#pragma unroll 1
    for (int tt = 0; tt < 8; ++tt) {
        step(2 * tt,     smem,        smem + BUFS, true);
        step(2 * tt + 1, smem + BUFS, smem,        true);
    }
    step(16, smem, smem + BUFS, false);

    const int b = bh / NHEADS, hh = bh - b * NHEADS;
#pragma unroll
    for (int h = 0; h < 2; ++h)
#pragma unroll
        for (int r = 0; r < 4; ++r) {
            int q = q0 + (wv << 5) + (h << 4) + (g << 2) + r;
            float linv = 1.0f / oa[h][4][r];
            if (q < NN) {
#pragma unroll
                for (int db = 0; db < 4; ++db) {
                    int d = (db << 4) + qi;
                    OC[(size_t)(b * NN + q) * CC + hh * HD + d] = f2h(oa[h][db][r] * linv);
                }
            }
        }
}

extern "C" void kernel_launch(void* const* d_in, const int* in_sizes, int n_in,
                              void* d_out, int out_size, void* d_ws, size_t ws_size,
                              hipStream_t stream) {
    const float* x      = (const float*)d_in[0];
    const float* qkv_w  = (const float*)d_in[1];
    const float* proj_w = (const float*)d_in[2];
    const float* proj_b = (const float*)d_in[3];
    const float* qnw    = (const float*)d_in[4];
    const float* knw    = (const float*)d_in[5];

    us* p = (us*)d_ws;
    us* Q   = p;                 p += QSZ;
    us* K   = p;                 p += QSZ;
    us* Vth = p;                 p += VTSZ;
    us* XC  = p;                 p += (size_t)MM * CC;     // plain fp16 X; reused as O
    us* WC  = p;                 p += (size_t)3 * CC * CC; // qkv W^T plain fp16
    us* PC  = p;                 p += (size_t)CC * CC;     // proj W^T plain fp16

    split_x<<<dim3((int)(((size_t)MM * CC) / 8 / 256)), 256, 0, stream>>>(x, XC);
    tsplit<<<dim3(3 * CC / 64, CC / 64), 256, 0, stream>>>(qkv_w, WC, 3 * CC);
    tsplit<<<dim3(CC / 64, CC / 64), 256, 0, stream>>>(proj_w, PC, CC);

    gemm_mfma<0><<<dim3(18, (MM + 255) / 256), 512, 0, stream>>>(
        WC, XC, Q, K, Vth, qnw, knw, nullptr, nullptr);
    attn_mfma<<<dim3(8 * 216), 256, 0, stream>>>(Q, K, Vth, XC);
    gemm_mfma<1><<<dim3(6, (MM + 255) / 256), 512, 0, stream>>>(
        PC, XC, nullptr, nullptr, nullptr, nullptr, nullptr,
        (float*)d_out, proj_b);
}

// Round 29
// 219.506 us; speedup vs baseline: 1.0400x; 1.0400x over previous
//
#include <hip/hip_runtime.h>
#include <math.h>

#define NHEADS 12
#define HD 64
#define BB 16
#define NN 1025
#define CC 768
#define MM (BB * NN)                       // 16400
#define QSZ ((size_t)BB * NHEADS * NN * HD)   // 12,595,200
#define NNP 1032                           // padded t-stride for V^T
#define VTSZ ((size_t)BB * NHEADS * HD * NNP)

typedef __attribute__((ext_vector_type(8))) short short8;
typedef __attribute__((ext_vector_type(4))) float f32x4;
typedef __attribute__((ext_vector_type(4))) unsigned short us4;
typedef __attribute__((ext_vector_type(4))) unsigned int u32x4;
typedef unsigned short us;

typedef __attribute__((address_space(3))) unsigned int lds_u32;
typedef const __attribute__((address_space(1))) unsigned int g_u32;

__device__ __forceinline__ void gload16(const void* g, void* l) {
    __builtin_amdgcn_global_load_lds((g_u32*)g, (lds_u32*)l, 16, 0, 0);
}

__device__ __forceinline__ int imin(int a, int b) { return a < b ? a : b; }

__device__ __forceinline__ us f2h(float f) {          // fp32 -> fp16 bits (RTE)
    _Float16 h = (_Float16)f;
    return __builtin_bit_cast(unsigned short, h);
}
__device__ __forceinline__ float h2f(us b) {
    return (float)__builtin_bit_cast(_Float16, b);
}
__device__ __forceinline__ unsigned pkrtz(float a, float b) {  // 2xfp16 packed
    return __builtin_bit_cast(unsigned, __builtin_amdgcn_cvt_pkrtz(a, b));
}

// ---------------- split_x: fp32 -> plain fp16 [M][768] -----------------------------
__global__ __launch_bounds__(256) void split_x(const float* __restrict__ src,
                                               us* __restrict__ xc) {
    size_t e = ((size_t)blockIdx.x * 256 + threadIdx.x) * 8;
    float4 a = *(const float4*)(src + e);
    float4 b = *(const float4*)(src + e + 4);
    float v[8] = {a.x, a.y, a.z, a.w, b.x, b.y, b.z, b.w};
    short8 h;
#pragma unroll
    for (int j = 0; j < 8; ++j) h[j] = (short)f2h(v[j]);
    *(short8*)(xc + e) = h;
}

// ---------------- tsplit: W [K][N] fp32 -> W^T plain fp16 [N][K] -------------------
__global__ __launch_bounds__(256) void tsplit(const float* __restrict__ w,
                                              us* __restrict__ wc, int N) {
    __shared__ float tile[64][65];
    const int t = threadIdx.x;
    const int n0 = blockIdx.x * 64, k0 = blockIdx.y * 64;
    {
        int kr = t & 63, so = t >> 6;
#pragma unroll
        for (int g = 0; g < 4; ++g) {
            int c = (so * 4 + g) * 4;
            float4 v = *(const float4*)(w + (size_t)(k0 + kr) * N + n0 + c);
            tile[kr][c + 0] = v.x; tile[kr][c + 1] = v.y;
            tile[kr][c + 2] = v.z; tile[kr][c + 3] = v.w;
        }
    }
    __syncthreads();
    int nr = t & 63, half = t >> 6;     // 16 consecutive k per thread
    short8 h0, h1;
#pragma unroll
    for (int j = 0; j < 8; ++j) h0[j] = (short)f2h(tile[half * 16 + j][nr]);
#pragma unroll
    for (int j = 0; j < 8; ++j) h1[j] = (short)f2h(tile[half * 16 + 8 + j][nr]);
    size_t o = (size_t)(n0 + nr) * CC + k0 + half * 16;
    *(short8*)(wc + o)     = h0;
    *(short8*)(wc + o + 8) = h1;
}

// ---------------- gemm_mfma: 256Mx128N tile, 512 thr (8 waves), gload_lds ----------
// MODE 0: qkv epilogue with FUSED RMSNorm+RoPE for Q/K (LUT in reused LDS).
template<int MODE>
__global__ __launch_bounds__(512) void gemm_mfma(
    const us* __restrict__ A,      // W^T plain fp16 [N][768]
    const us* __restrict__ B,      // X/O plain fp16 [M][768]
    us* __restrict__ Q, us* __restrict__ K, us* __restrict__ Vth,
    const float* __restrict__ qnw, const float* __restrict__ knw,
    float* __restrict__ fout, const float* __restrict__ bias) {
    __shared__ __align__(16) char lds[49152];
    char* ldsA = lds;              // 16 KB: 128 rows x 128B
    char* ldsB = lds + 16384;      // 32 KB: 256 rows x 128B
    const int tid = threadIdx.x;
    const int lane = tid & 63, wv = tid >> 6;   // 8 waves
    const int wn = wv >> 2, wm = wv & 3;        // 2n x 4m
    const int g = lane >> 4;

    // bijective XCD swizzle (m204)
    const int gx = gridDim.x;
    const int nwg = gx * gridDim.y;
    const int lin = blockIdx.y * gx + blockIdx.x;
    const int qq = nwg >> 3, rr = nwg & 7;
    const int xcd = lin & 7, idx = lin >> 3;
    const int wgid = (xcd < rr ? xcd * (qq + 1) : rr * (qq + 1) + (xcd - rr) * qq) + idx;
    const int n0 = (wgid % gx) * 128, m0 = (wgid / gx) * 256;

    f32x4 acc[4][4];
    const f32x4 fz = {0.f, 0.f, 0.f, 0.f};
#pragma unroll
    for (int a = 0; a < 4; ++a)
#pragma unroll
        for (int b = 0; b < 4; ++b) acc[a][b] = fz;

    const int srow = (wv << 3) + (lane >> 3);   // 0..63
    const int cb   = (lane & 7) ^ ((lane >> 3) & 7);
    size_t aoff[2], boff[4];
#pragma unroll
    for (int i = 0; i < 2; ++i)
        aoff[i] = (size_t)(n0 + i * 64 + srow) * CC + cb * 8;
#pragma unroll
    for (int i = 0; i < 4; ++i)
        boff[i] = (size_t)imin(m0 + i * 64 + srow, MM - 1) * CC + cb * 8;
    const int wdst = wv * 1024;    // (wv*8 rows) * 128B

    for (int t = 0; t < CC / 64; ++t) {
#pragma unroll
        for (int i = 0; i < 2; ++i)
            gload16(A + aoff[i] + t * 64, ldsA + i * 8192 + wdst);
#pragma unroll
        for (int i = 0; i < 4; ++i)
            gload16(B + boff[i] + t * 64, ldsB + i * 8192 + wdst);
        __syncthreads();

        const int j  = lane >> 4;
        const int rl = lane & 15;
#pragma unroll
        for (int kh = 0; kh < 2; ++kh) {
            short8 af[4];
#pragma unroll
            for (int nc = 0; nc < 4; ++nc) {
                int ra = wn * 64 + nc * 16 + rl;
                af[nc] = *(const short8*)(ldsA + ra * 128 + ((((kh << 2) + j) ^ (ra & 7)) << 4));
            }
            __builtin_amdgcn_s_setprio(1);
#pragma unroll
            for (int mc = 0; mc < 4; ++mc) {
                int rb = wm * 64 + mc * 16 + rl;
                short8 bf = *(const short8*)(ldsB + rb * 128 + ((((kh << 2) + j) ^ (rb & 7)) << 4));
#pragma unroll
                for (int nc = 0; nc < 4; ++nc)
                    acc[nc][mc] = __builtin_amdgcn_mfma_f32_16x16x32_f16(af[nc], bf, acc[nc][mc], 0, 0, 0);
            }
            __builtin_amdgcn_s_setprio(0);
        }
        __syncthreads();
    }

    if (MODE == 0) {
        const int s = n0 / CC;
        if (s < 2) {
            // ---- fused RMSNorm + RoPE on Q/K rows (row m fully held by 4 g-lanes) --
            float2* lut = (float2*)lds;       // reuse LDS: 512 x (cos,sin)
            {
                int pos = tid >> 4, jj = tid & 15;
                float ang = (float)pos * exp2f((float)jj * (-13.287712379549449f / 16.0f));
                lut[tid] = make_float2(cosf(ang), sinf(ang));
            }
            __syncthreads();
            const float* wvec = (s == 0) ? qnw : knw;
            float wr[4][4];
#pragma unroll
            for (int nc = 0; nc < 4; ++nc)
#pragma unroll
                for (int r = 0; r < 4; ++r) wr[nc][r] = wvec[nc * 16 + g * 4 + r];
            const float qscale = (s == 0) ? 0.125f * 1.4426950408889634f : 1.0f;
            const int head = (n0 - s * CC + wn * 64) >> 6;   // wave-uniform
            us* dst = (s == 0) ? Q : K;

#pragma unroll
            for (int mc = 0; mc < 4; ++mc) {
                int m = m0 + wm * 64 + mc * 16 + (lane & 15);
                if (m >= MM) continue;
                int b = m / NN, t = m - b * NN;
                float v[4][4];
#pragma unroll
                for (int nc = 0; nc < 4; ++nc)
#pragma unroll
                    for (int r = 0; r < 4; ++r) v[nc][r] = acc[nc][mc][r];
                float ss = 0.f;
#pragma unroll
                for (int nc = 0; nc < 4; ++nc)
#pragma unroll
                    for (int r = 0; r < 4; ++r) ss += v[nc][r] * v[nc][r];
                ss += __shfl_xor(ss, 16);
                ss += __shfl_xor(ss, 32);
                float rn = 1.0f / sqrtf(ss * (1.0f / 64.0f) + 1e-6f);
#pragma unroll
                for (int nc = 0; nc < 4; ++nc)
#pragma unroll
                    for (int r = 0; r < 4; ++r) v[nc][r] *= rn * wr[nc][r];
                if (t > 0) {
                    int px = (t - 1) & 31, py = (t - 1) >> 5;
#pragma unroll
                    for (int r = 0; r < 4; ++r) {
                        float2 ex = lut[px * 16 + g * 4 + r];
                        float2 ey = lut[py * 16 + g * 4 + r];
                        float n0v = v[0][r] * ex.x - v[2][r] * ex.y;
                        float n1v = v[1][r] * ex.x - v[3][r] * ex.y;
                        float n2v = v[2][r] * ey.x + v[0][r] * ey.y;
                        float n3v = v[3][r] * ey.x + v[1][r] * ey.y;
                        v[0][r] = n0v; v[1][r] = n1v; v[2][r] = n2v; v[3][r] = n3v;
                    }
                }
                int bh = b * NHEADS + head;
                size_t rbase = ((size_t)bh * NN + t) * HD;
#pragma unroll
                for (int nc = 0; nc < 4; ++nc) {
                    us4 h4;
#pragma unroll
                    for (int r = 0; r < 4; ++r) h4[r] = f2h(v[nc][r] * qscale);
                    *(us4*)(dst + rbase + nc * 16 + g * 4) = h4;
                }
            }
        } else {
            // ---- V epilogue (transposed store, pads zeroed) ----
#pragma unroll
            for (int mc = 0; mc < 4; ++mc) {
                int m = m0 + wm * 64 + mc * 16 + (lane & 15);
                if (m >= MM) continue;
                int b = m / NN, t = m - b * NN;
#pragma unroll
                for (int nc = 0; nc < 4; ++nc) {
                    int nin = (n0 - 2 * CC) + wn * 64 + nc * 16 + g * 4;  // head*64+d
                    int head = nin >> 6;
                    int dd = nin & 63;
                    int bh = b * NHEADS + head;
#pragma unroll
                    for (int r = 0; r < 4; ++r) {
                        size_t idx2 = ((size_t)bh * HD + dd + r) * NNP + t;
                        Vth[idx2] = f2h(acc[nc][mc][r]);
                        if (t == NN - 1) {
#pragma unroll
                            for (int tt = 1; tt <= 7; ++tt) Vth[idx2 + tt] = 0;
                        }
                    }
                }
            }
        }
    } else {
#pragma unroll
        for (int mc = 0; mc < 4; ++mc) {
            int m = m0 + wm * 64 + mc * 16 + (lane & 15);
            if (m >= MM) continue;
#pragma unroll
            for (int nc = 0; nc < 4; ++nc) {
                int n = n0 + wn * 64 + nc * 16 + (g << 2);
                float4 o = {acc[nc][mc][0] + bias[n + 0], acc[nc][mc][1] + bias[n + 1],
                            acc[nc][mc][2] + bias[n + 2], acc[nc][mc][3] + bias[n + 3]};
                *(float4*)(fout + (size_t)m * CC + n) = o;
            }
        }
    }
}

// ---------------- attn: gload_lds dbuf (pre-permuted src), SEQUENTIAL q-halves -----
// sigma(pp) = p5<<5 | p3<<4 | p2<<3 | p4<<2 | p1<<1 | p0  (verified r28)
// r26's register discipline: sc[4] reused per half -> VGPR low, occupancy high.
__global__ __launch_bounds__(256, 4) void attn_mfma(
    const us* __restrict__ Q, const us* __restrict__ K,
    const us* __restrict__ Vth, us* __restrict__ OC) {
    __shared__ __align__(16) char smem[36864];
    const int tid = threadIdx.x;
    const int lane = tid & 63, wv = tid >> 6;
    const int g = lane >> 4, qi = lane & 15;

    int lin = blockIdx.x;                  // 0..1727
    int xcd = lin & 7, loc = lin >> 3;     // loc 0..215
    int bh  = (loc / 9) * 8 + xcd;         // 0..191
    int qb  = loc - (loc / 9) * 9;         // 0..8
    const int q0 = qb * 128;

    const size_t kbase0 = (size_t)bh * NN * HD;
    const size_t vbase0 = (size_t)bh * HD * NNP;

    short8 qf[2][2];
#pragma unroll
    for (int h = 0; h < 2; ++h) {
        int qr = imin(q0 + (wv << 5) + (h << 4) + qi, NN - 1);
        const us* qp = Q + kbase0 + (size_t)qr * HD + (g << 3);
        qf[h][0] = *(const short8*)(qp);
        qf[h][1] = *(const short8*)(qp + 32);
    }

    f32x4 oa[2][5];                // [h][4] = denominator (V ones-rows)
    const f32x4 fz = {0.f, 0.f, 0.f, 0.f};
#pragma unroll
    for (int h = 0; h < 2; ++h)
#pragma unroll
        for (int db = 0; db < 5; ++db) oa[h][db] = fz;

    const int VB = 8192;           // V offset within a buffer (buffer = 18432 B)
    const int BUFS = 18432;

    // ones rows d=64..79 of BOTH V buffers
    *(uint2*)(smem + VB + 8192 + tid * 8) = (uint2){0x3C003C00u, 0x3C003C00u};
    *(uint2*)(smem + BUFS + VB + 8192 + tid * 8) = (uint2){0x3C003C00u, 0x3C003C00u};

    int rbase[2];
#pragma unroll
    for (int ks = 0; ks < 2; ++ks)
        rbase[ks] = qi * 128 + (((ks << 6) + (g << 4)) ^ ((qi & 7) << 4));

    // gload_lds staging: lane l of wave's 8-row chunk -> LDS row pp, slot l&7.
    // K source pre-permuted: true key sigma(pp), chunk (l&7)^(pp&7).
    const int lrow = lane >> 3, lslot = lane & 7;
    const us* ks_[2];
    const us* vs_[2];
#pragma unroll
    for (int i = 0; i < 2; ++i) {
        int pp  = (wv << 4) + (i << 3) + lrow;
        int sig = ((pp >> 5) << 5) | (((pp >> 3) & 1) << 4) |
                  (((pp >> 2) & 1) << 3) | (((pp >> 4) & 1) << 2) | (pp & 3);
        ks_[i] = K + kbase0 + (size_t)sig * HD + ((lslot ^ (pp & 7)) << 3);
        vs_[i] = Vth + vbase0 + (size_t)pp * NNP + ((lslot ^ lrow) << 3);
    }
    const int kd0 = wv * 2048, kd1 = wv * 2048 + 1024;

    // prologue: stage tile 0 into buf0
    gload16(ks_[0], smem + kd0);
    gload16(ks_[1], smem + kd1);
    gload16(vs_[0], smem + VB + kd0);
    gload16(vs_[1], smem + VB + kd1);
    ks_[0] += 64 * HD; ks_[1] += 64 * HD; vs_[0] += 64; vs_[1] += 64;
    __syncthreads();

    auto step = [&](int t, char* buf, char* bufn, bool stage) {
        if (stage) {               // issue t+1 loads into the other buffer
            gload16(ks_[0], bufn + kd0);
            gload16(ks_[1], bufn + kd1);
            gload16(vs_[0], bufn + VB + kd0);
            gload16(vs_[1], bufn + VB + kd1);
            ks_[0] += 64 * HD; ks_[1] += 64 * HD; vs_[0] += 64; vs_[1] += 64;
        }
        const int j0 = t * 64;

        // per q-half (sequential, sc[4] reused): S^T = K·Q, mask, p = exp2(s)
        short8 pa[2][2];
#pragma unroll
        for (int h = 0; h < 2; ++h) {
            f32x4 sc[4];
#pragma unroll
            for (int c = 0; c < 4; ++c) sc[c] = fz;
            __builtin_amdgcn_s_setprio(1);
#pragma unroll
            for (int ks = 0; ks < 2; ++ks)
#pragma unroll
                for (int c = 0; c < 4; ++c) {
                    short8 kfh = *(const short8*)(buf + rbase[ks] + c * 2048);
                    sc[c] = __builtin_amdgcn_mfma_f32_16x16x32_f16(kfh, qf[h][ks], sc[c], 0, 0, 0);
                }
            __builtin_amdgcn_s_setprio(0);

            if (j0 + 64 > NN) {   // TRUE key of frag (c,r) = 32(c>>1)+8g+4(c&1)+r
#pragma unroll
                for (int c = 0; c < 4; ++c)
#pragma unroll
                    for (int r = 0; r < 4; ++r)
                        if (j0 + ((c >> 1) << 5) + (g << 3) + ((c & 1) << 2) + r >= NN)
                            sc[c][r] = -1e30f;
            }
#pragma unroll
            for (int ks = 0; ks < 2; ++ks) {
                u32x4 w;
                w[0] = pkrtz(exp2f(sc[2 * ks][0]), exp2f(sc[2 * ks][1]));
                w[1] = pkrtz(exp2f(sc[2 * ks][2]), exp2f(sc[2 * ks][3]));
                w[2] = pkrtz(exp2f(sc[2 * ks + 1][0]), exp2f(sc[2 * ks + 1][1]));
                w[3] = pkrtz(exp2f(sc[2 * ks + 1][2]), exp2f(sc[2 * ks + 1][3]));
                pa[h][ks] = __builtin_bit_cast(short8, w);
            }
        }

        // O += P·V; l += P·ones (db=4); V fragment shared across halves
        __builtin_amdgcn_s_setprio(1);
#pragma unroll
        for (int ks = 0; ks < 2; ++ks)
#pragma unroll
            for (int db = 0; db < 5; ++db) {
                short8 vfh = *(const short8*)(buf + VB + rbase[ks] + db * 2048);
                oa[0][db] = __builtin_amdgcn_mfma_f32_16x16x32_f16(pa[0][ks], vfh, oa[0][db], 0, 0, 0);
                oa[1][db] = __builtin_amdgcn_mfma_f32_16x16x32_f16(pa[1][ks], vfh, oa[1][db], 0, 0, 0);
            }
        __builtin_amdgcn_s_setprio(0);
        __syncthreads();
    };

#pragma unroll 1
    for (int tt = 0; tt < 8; ++tt) {
        step(2 * tt,     smem,        smem + BUFS, true);
        step(2 * tt + 1, smem + BUFS, smem,        true);
    }
    step(16, smem, smem + BUFS, false);

    const int b = bh / NHEADS, hh = bh - b * NHEADS;
#pragma unroll
    for (int h = 0; h < 2; ++h)
#pragma unroll
        for (int r = 0; r < 4; ++r) {
            int q = q0 + (wv << 5) + (h << 4) + (g << 2) + r;
            float linv = 1.0f / oa[h][4][r];
            if (q < NN) {
#pragma unroll
                for (int db = 0; db < 4; ++db) {
                    int d = (db << 4) + qi;
                    OC[(size_t)(b * NN + q) * CC + hh * HD + d] = f2h(oa[h][db][r] * linv);
                }
            }
        }
}

extern "C" void kernel_launch(void* const* d_in, const int* in_sizes, int n_in,
                              void* d_out, int out_size, void* d_ws, size_t ws_size,
                              hipStream_t stream) {
    const float* x      = (const float*)d_in[0];
    const float* qkv_w  = (const float*)d_in[1];
    const float* proj_w = (const float*)d_in[2];
    const float* proj_b = (const float*)d_in[3];
    const float* qnw    = (const float*)d_in[4];
    const float* knw    = (const float*)d_in[5];

    us* p = (us*)d_ws;
    us* Q   = p;                 p += QSZ;
    us* K   = p;                 p += QSZ;
    us* Vth = p;                 p += VTSZ;
    us* XC  = p;                 p += (size_t)MM * CC;     // plain fp16 X; reused as O
    us* WC  = p;                 p += (size_t)3 * CC * CC; // qkv W^T plain fp16
    us* PC  = p;                 p += (size_t)CC * CC;     // proj W^T plain fp16

    split_x<<<dim3((int)(((size_t)MM * CC) / 8 / 256)), 256, 0, stream>>>(x, XC);
    tsplit<<<dim3(3 * CC / 64, CC / 64), 256, 0, stream>>>(qkv_w, WC, 3 * CC);
    tsplit<<<dim3(CC / 64, CC / 64), 256, 0, stream>>>(proj_w, PC, CC);

    gemm_mfma<0><<<dim3(18, (MM + 255) / 256), 512, 0, stream>>>(
        WC, XC, Q, K, Vth, qnw, knw, nullptr, nullptr);
    attn_mfma<<<dim3(8 * 216), 256, 0, stream>>>(Q, K, Vth, XC);
    gemm_mfma<1><<<dim3(6, (MM + 255) / 256), 512, 0, stream>>>(
        PC, XC, nullptr, nullptr, nullptr, nullptr, nullptr,
        (float*)d_out, proj_b);
}